// Round 1
// 9704.198 us; speedup vs baseline: 2.3858x; 2.3858x over previous
//
#include <hip/hip_runtime.h>
#include <math.h>

#define T_  512
#define B_  128
#define H_  256
#define A_  18
#define G4H 1024
#define TB_ (T_*B_)

// d_out layout (floats): [logits T*B*A][baseline T*B][action T*B][hT 2*B*H][cT 2*B*H]
#define OUT_BASE  (TB_*A_)
#define OUT_ACT   (OUT_BASE + TB_)
#define OUT_HT    (OUT_ACT + TB_)
#define OUT_CT    (OUT_HT + 2*B_*H_)

// workspace layout (floats): double-buffered h per layer (parity = t&1), private c per layer
#define WS_H0 0               // [2][B_][H_]
#define WS_H1 (2*B_*H_)       // [2][B_][H_]
#define WS_C0 (4*B_*H_)       // [B_][H_]
#define WS_C1 (5*B_*H_)       // [B_][H_]  -> total 6*B*H floats = 768 KB

#define PP 66   // part pitch: float2 reduce reads collide 4-way (1.58x, m136) - acceptable

// PIPELINED PER-STEP DISPATCH DESIGN.
// Dispatch d: 128 L0 WGs do step t=d, 128 L1 WGs do step t=d-1 (+ head for t=d-2).
// Kernel boundaries provide cross-WG ordering (stream-serial graph nodes) - no
// cooperative launch, no fences, no XCD coherence assumptions. Each WG = 16
// batches x 16 h-indices: weights read once per batch-TILE (8x reuse vs 1-WG-
// per-batch), 128 KB/CU/dispatch from L2/L3 instead of 4 MB/step/CU.
// wg%8 == hg%8 -> all batch-tiles of an h-group land on one XCD (L3 locality).

__global__ __launch_bounds__(256, 1) void lstm_step(
    const float* __restrict__ x, const int* __restrict__ done,
    const float* __restrict__ h0in, const float* __restrict__ c0in,
    const float* __restrict__ w_ih, const float* __restrict__ w_hh,
    const float* __restrict__ b_ih, const float* __restrict__ b_hh,
    const float* __restrict__ Wp, const float* __restrict__ bp,
    const float* __restrict__ Wb, const float* __restrict__ bb,
    float* __restrict__ out, float* __restrict__ ws, int d)
{
    __shared__ __align__(16) float part[512*PP];        // 135168 B
    __shared__ __align__(16) float gates[4][16][16];    // [gate][hi][j] 4 KB
    __shared__ float hlog[19];

    const int wg  = blockIdx.x;
    const int tid = threadIdx.x;
    const int l   = wg >> 7;          // 0: layer0, 1: layer1 (+head duty)
    const int wl  = wg & 127;
    const int t   = d - l;            // this WG's timestep

    if (t >= 0 && t < T_) {
        const int bt = wl >> 4, hg = wl & 15;     // 8 batch-tiles x 16 h-groups
        const int lane = tid & 63, w = tid >> 6;  // 4 waves
        const int b0 = bt*16;

        const float* WI = w_ih + (size_t)l*G4H*H_;
        const float* WH = w_hh + (size_t)l*G4H*H_;
        const float* BI = b_ih + l*G4H;
        const float* BH = b_hh + l*G4H;
        float* hout = ws + (l ? WS_H1 : WS_H0) + (size_t)(t&1)*B_*H_;
        const float* hrec = (t == 0) ? (h0in + (size_t)l*B_*H_)
                                     : (ws + (l ? WS_H1 : WS_H0) + (size_t)((t-1)&1)*B_*H_);
        const float* xin = l ? (ws + WS_H0 + (size_t)(t&1)*B_*H_)   // fresh h0(t), unmasked
                             : (x + (size_t)t*B_*H_);

        // ---- A in registers: 16 batches x (input float4 + masked recurrent float4) ----
        float4 xr[16], hr[16];
        #pragma unroll
        for (int j = 0; j < 16; ++j) {
            const int b = b0 + j;
            float nd = done[t*B_ + b] ? 0.f : 1.f;
            xr[j] = ((const float4*)(xin + (size_t)b*H_))[lane];
            float4 h4 = ((const float4*)(hrec + (size_t)b*H_))[lane];
            hr[j] = make_float4(h4.x*nd, h4.y*nd, h4.z*nd, h4.w*nd);
        }

        // ---- 64 gate-rows in two halves (part[] = 128 KB per half) ----
        #pragma unroll
        for (int half = 0; half < 2; ++half) {
            const int g   = half*2 + (w >> 1);
            const int i0  = (w & 1)*8;
            const int rhb = (w >> 1)*16 + i0;       // row-in-half base (0..31)
            #pragma unroll 2
            for (int rr = 0; rr < 8; ++rr) {
                const int r = g*256 + hg*16 + i0 + rr;
                float4 wi4 = ((const float4*)(WI + (size_t)r*H_))[lane];   // 1 KB/row coalesced
                float4 wh4 = ((const float4*)(WH + (size_t)r*H_))[lane];
                float* pr = part + (size_t)((rhb + rr)*16)*PP + lane;      // stride-1 lanes: free
                #pragma unroll
                for (int j = 0; j < 16; ++j) {
                    float s = wi4.x*xr[j].x + wi4.y*xr[j].y + wi4.z*xr[j].z + wi4.w*xr[j].w
                            + wh4.x*hr[j].x + wh4.y*hr[j].y + wh4.z*hr[j].z + wh4.w*hr[j].w;
                    pr[(size_t)j*PP] = s;
                }
            }
            __syncthreads();
            #pragma unroll
            for (int oo = 0; oo < 2; ++oo) {
                const int oi = oo*256 + tid;        // 512 outputs this half
                const int rh = oi >> 4, j = oi & 15;
                const float2* p2 = (const float2*)(part + (size_t)oi*PP);
                float sx = 0.f, sy = 0.f;
                #pragma unroll
                for (int q = 0; q < 32; ++q) { float2 v = p2[q]; sx += v.x; sy += v.y; }
                const int gg = half*2 + (rh >> 4);
                const int r  = gg*256 + hg*16 + (rh & 15);
                gates[gg][rh & 15][j] = sx + sy + BI[r] + BH[r];
            }
            __syncthreads();
        }

        // ---- cell update (i,f,g,o): thread = (batch j, h-index hi) ----
        {
            const int j = tid >> 4, hi = tid & 15;
            const int b = b0 + j, h = hg*16 + hi;
            float nd = done[t*B_ + b] ? 0.f : 1.f;
            float* cst = ws + (l ? WS_C1 : WS_C0) + (size_t)b*H_ + h;
            float cp = ((t == 0) ? c0in[(size_t)l*B_*H_ + b*H_ + h] : *cst) * nd;
            float gi = gates[0][hi][j], gf = gates[1][hi][j];
            float gv = gates[2][hi][j], go = gates[3][hi][j];
            float ii = 1.f/(1.f + expf(-gi));
            float ff = 1.f/(1.f + expf(-gf));
            float gt = tanhf(gv);
            float oo = 1.f/(1.f + expf(-go));
            float cl = ff*cp + ii*gt;
            *cst = cl;
            hout[(size_t)b*H_ + h] = oo*tanhf(cl);
        }
    }

    // ---- head (t = d-2) + final state copies, on layer-1 WGs (1 batch each) ----
    if (l == 1) {
        const int th = d - 2;                 // <= 511 since d <= 513
        if (th >= 0) {
            const int b = wl;
            const int lane = tid & 63, w = tid >> 6;
            const float* h1 = ws + WS_H1 + (size_t)(th&1)*B_*H_ + (size_t)b*H_;
            float4 h4 = ((const float4*)h1)[lane];
            const int acnt = (w == 3) ? 4 : 5;          // rows: 0-4,5-9,10-14,15-18
            for (int q = 0; q < acnt; ++q) {
                const int a = w*5 + q;
                const float* wr = (a < 18) ? (Wp + a*H_) : Wb;
                float4 w4 = ((const float4*)wr)[lane];
                float s = w4.x*h4.x + w4.y*h4.y + w4.z*h4.z + w4.w*h4.w;
                s += __shfl_xor(s, 1);  s += __shfl_xor(s, 2);  s += __shfl_xor(s, 4);
                s += __shfl_xor(s, 8);  s += __shfl_xor(s, 16); s += __shfl_xor(s, 32);
                if (lane == 0) hlog[a] = s + ((a < 18) ? bp[a] : bb[0]);
            }
            __syncthreads();
            if (tid < 18) {
                out[((size_t)th*B_ + b)*A_ + tid] = hlog[tid];
            } else if (tid == 32) {
                out[OUT_BASE + th*B_ + b] = hlog[18];
            } else if (tid == 64) {
                float best = hlog[0]; int bi = 0;
                #pragma unroll
                for (int a = 1; a < A_; ++a) { float v = hlog[a]; if (v > best) { best = v; bi = a; } }
                out[OUT_ACT + th*B_ + b] = (float)bi;     // strict > = first-max, matches np
            }
        }
        if (d == 513) {       // h(511) lives in parity slot 1; c states are current
            const int idx = wl*H_ + tid;      // 0..32767 = b*H + h
            out[OUT_HT + idx]           = ws[WS_H0 + B_*H_ + idx];
            out[OUT_HT + B_*H_ + idx]   = ws[WS_H1 + B_*H_ + idx];
            out[OUT_CT + idx]           = ws[WS_C0 + idx];
            out[OUT_CT + B_*H_ + idx]   = ws[WS_C1 + idx];
        }
    }
}

extern "C" void kernel_launch(void* const* d_in, const int* in_sizes, int n_in,
                              void* d_out, int out_size, void* d_ws, size_t ws_size,
                              hipStream_t stream)
{
    const float* x    = (const float*)d_in[0];
    const int*   done = (const int*)  d_in[1];
    const float* h0   = (const float*)d_in[2];
    const float* c0   = (const float*)d_in[3];
    const float* w_ih = (const float*)d_in[4];
    const float* w_hh = (const float*)d_in[5];
    const float* b_ih = (const float*)d_in[6];
    const float* b_hh = (const float*)d_in[7];
    const float* Wp   = (const float*)d_in[8];
    const float* bp   = (const float*)d_in[9];
    const float* Wb   = (const float*)d_in[10];
    const float* bb   = (const float*)d_in[11];
    float* out = (float*)d_out;
    float* ws  = (float*)d_ws;    // needs 6*B*H floats = 768 KB

    // 514 graph-captured dispatches: d = t for L0, t+1 for L1, t+2 for head
    for (int d = 0; d < 514; ++d) {
        lstm_step<<<dim3(256), dim3(256), 0, stream>>>(
            x, done, h0, c0, w_ih, w_hh, b_ih, b_hh, Wp, bp, Wb, bb, out, ws, d);
    }
}

// Round 2
// 6792.329 us; speedup vs baseline: 3.4087x; 1.4287x over previous
//
#include <hip/hip_runtime.h>
#include <math.h>

#define T_  512
#define B_  128
#define H_  256
#define A_  18
#define G4H 1024
#define TB_ (T_*B_)

// d_out layout (floats): [logits T*B*A][baseline T*B][action T*B][hT 2*B*H][cT 2*B*H]
#define OUT_BASE  (TB_*A_)
#define OUT_ACT   (OUT_BASE + TB_)
#define OUT_HT    (OUT_ACT + TB_)
#define OUT_CT    (OUT_HT + 2*B_*H_)

// workspace (floats): double-buffered h per layer (parity = t&1), private c per layer
#define WS_H0 0               // [2][B_][H_]
#define WS_H1 (2*B_*H_)       // [2][B_][H_]
#define WS_C0 (4*B_*H_)       // [B_][H_]
#define WS_C1 (5*B_*H_)       // [B_][H_]   total 768 KB

// PIPELINED PER-STEP DISPATCH, v2: 8 waves/WG (2 waves/SIMD for latency hiding),
// shuffle-reduce instead of LDS part buffer (was 135 KB + 2.8e8 bank-conflict
// cycles + 2 extra barriers). Lane split: kc = lane&15 owns K-slice of 16 floats
// (k-map k = q*64 + kc*4, keeps every load a contiguous 256B-1KB segment),
// jq = lane>>4 owns 4 batches. Partials reduced across the 16-lane kc group with
// 4 __shfl_xor steps. One __syncthreads per kernel (gates -> cell update).
// Head (t=d-2) runs FIRST on L1 WGs so its loads overlap weight streaming.

__global__ __launch_bounds__(512, 2) void lstm_step(
    const float* __restrict__ x, const int* __restrict__ done,
    const float* __restrict__ h0in, const float* __restrict__ c0in,
    const float* __restrict__ w_ih, const float* __restrict__ w_hh,
    const float* __restrict__ b_ih, const float* __restrict__ b_hh,
    const float* __restrict__ Wp, const float* __restrict__ bp,
    const float* __restrict__ Wb, const float* __restrict__ bb,
    float* __restrict__ out, float* __restrict__ ws, int d)
{
    __shared__ __align__(16) float gates[4][16][17];   // [gate][hi][j(+pad)] 4.25 KB
    __shared__ float hlog[19];

    const int wg   = blockIdx.x;
    const int tid  = threadIdx.x;
    const int l    = wg >> 7;            // 0: layer0, 1: layer1 (+head duty)
    const int wl   = wg & 127;
    const int t    = d - l;
    const int lane = tid & 63;
    const int w    = tid >> 6;           // wave 0..7
    const int kc   = lane & 15;          // K-chunk owner
    const int jq   = lane >> 4;          // batch-quad owner
    const bool work   = (t >= 0 && t < T_);
    const bool dohead = (l == 1 && d >= 2);

    const int bt = wl >> 4, hg = wl & 15, b0 = bt * 16;

    // ---- head for t = d-2 (independent of this dispatch's compute) ----
    if (dohead) {
        const int th = d - 2;
        const int b  = wl;
        const float* h1p = ws + WS_H1 + (size_t)(th & 1)*B_*H_ + (size_t)b*H_;
        float4 h4 = ((const float4*)h1p)[lane];
        for (int a = w; a < 19; a += 8) {
            const float* wr = (a < 18) ? (Wp + (size_t)a*H_) : Wb;
            float4 w4 = ((const float4*)wr)[lane];
            float s = w4.x*h4.x + w4.y*h4.y + w4.z*h4.z + w4.w*h4.w;
            s += __shfl_xor(s, 1);  s += __shfl_xor(s, 2);  s += __shfl_xor(s, 4);
            s += __shfl_xor(s, 8);  s += __shfl_xor(s, 16); s += __shfl_xor(s, 32);
            if (lane == 0) {
                float v = s + ((a < 18) ? bp[a] : bb[0]);
                hlog[a] = v;
                if (a < 18) out[((size_t)th*B_ + b)*A_ + a] = v;
                else        out[OUT_BASE + th*B_ + b] = v;
            }
        }
    }

    // ---- gate phase ----
    if (work) {
        const float* WI = w_ih + (size_t)l*G4H*H_;
        const float* WH = w_hh + (size_t)l*G4H*H_;
        const float* hrec = (t == 0) ? (h0in + (size_t)l*B_*H_)
                                     : (ws + (l ? WS_H1 : WS_H0) + (size_t)((t-1)&1)*B_*H_);
        const float* xin  = l ? (ws + WS_H0 + (size_t)(t&1)*B_*H_)   // fresh h0(t), unmasked
                              : (x + (size_t)t*B_*H_);

        // activations in registers: 4 batches x 16 K-floats each for x and masked h
        float4 xr[4][4], hr[4][4];
        #pragma unroll
        for (int jj = 0; jj < 4; ++jj) {
            const int b = b0 + jq*4 + jj;
            const float nd = done[t*B_ + b] ? 0.f : 1.f;
            const float4* xb = (const float4*)(xin  + (size_t)b*H_);
            const float4* hb = (const float4*)(hrec + (size_t)b*H_);
            #pragma unroll
            for (int q = 0; q < 4; ++q) {
                xr[jj][q] = xb[q*16 + kc];            // k = q*64 + kc*4 .. +3
                float4 h4 = hb[q*16 + kc];
                hr[jj][q] = make_float4(h4.x*nd, h4.y*nd, h4.z*nd, h4.w*nd);
            }
        }

        // 8 gate rows per wave; per row: 8 coalesced 256B loads, 128 FMA,
        // 16 shuffle-adds, 1 LDS write (lanes kc<4)
        #pragma unroll 2
        for (int rr = 0; rr < 8; ++rr) {
            const int wr = w*8 + rr;
            const int g  = wr >> 4, ri = wr & 15;
            const int r  = g*256 + hg*16 + ri;
            const float4* wi = (const float4*)(WI + (size_t)r*H_);
            const float4* wh = (const float4*)(WH + (size_t)r*H_);
            float4 wiv[4], whv[4];
            #pragma unroll
            for (int q = 0; q < 4; ++q) { wiv[q] = wi[q*16 + kc]; whv[q] = wh[q*16 + kc]; }
            float acc0 = 0.f, acc1 = 0.f, acc2 = 0.f, acc3 = 0.f;
            #pragma unroll
            for (int q = 0; q < 4; ++q) {
                acc0 += wiv[q].x*xr[0][q].x + wiv[q].y*xr[0][q].y + wiv[q].z*xr[0][q].z + wiv[q].w*xr[0][q].w
                      + whv[q].x*hr[0][q].x + whv[q].y*hr[0][q].y + whv[q].z*hr[0][q].z + whv[q].w*hr[0][q].w;
                acc1 += wiv[q].x*xr[1][q].x + wiv[q].y*xr[1][q].y + wiv[q].z*xr[1][q].z + wiv[q].w*xr[1][q].w
                      + whv[q].x*hr[1][q].x + whv[q].y*hr[1][q].y + whv[q].z*hr[1][q].z + whv[q].w*hr[1][q].w;
                acc2 += wiv[q].x*xr[2][q].x + wiv[q].y*xr[2][q].y + wiv[q].z*xr[2][q].z + wiv[q].w*xr[2][q].w
                      + whv[q].x*hr[2][q].x + whv[q].y*hr[2][q].y + whv[q].z*hr[2][q].z + whv[q].w*hr[2][q].w;
                acc3 += wiv[q].x*xr[3][q].x + wiv[q].y*xr[3][q].y + wiv[q].z*xr[3][q].z + wiv[q].w*xr[3][q].w
                      + whv[q].x*hr[3][q].x + whv[q].y*hr[3][q].y + whv[q].z*hr[3][q].z + whv[q].w*hr[3][q].w;
            }
            // reduce across the 16-lane kc group (jq-private)
            acc0 += __shfl_xor(acc0, 1, 16); acc0 += __shfl_xor(acc0, 2, 16);
            acc0 += __shfl_xor(acc0, 4, 16); acc0 += __shfl_xor(acc0, 8, 16);
            acc1 += __shfl_xor(acc1, 1, 16); acc1 += __shfl_xor(acc1, 2, 16);
            acc1 += __shfl_xor(acc1, 4, 16); acc1 += __shfl_xor(acc1, 8, 16);
            acc2 += __shfl_xor(acc2, 1, 16); acc2 += __shfl_xor(acc2, 2, 16);
            acc2 += __shfl_xor(acc2, 4, 16); acc2 += __shfl_xor(acc2, 8, 16);
            acc3 += __shfl_xor(acc3, 1, 16); acc3 += __shfl_xor(acc3, 2, 16);
            acc3 += __shfl_xor(acc3, 4, 16); acc3 += __shfl_xor(acc3, 8, 16);
            float v = (kc == 0) ? acc0 : (kc == 1) ? acc1 : (kc == 2) ? acc2 : acc3;
            if (kc < 4)
                gates[g][ri][jq*4 + kc] = v + b_ih[(size_t)l*G4H + r] + b_hh[(size_t)l*G4H + r];
        }
    }

    __syncthreads();   // uniform: every thread of the WG reaches this

    // ---- cell update (i,f,g,o): 256 (batch, h) pairs ----
    if (work && tid < 256) {
        const int j = tid >> 4, hi = tid & 15;
        const int b = b0 + j, h = hg*16 + hi;
        const float nd = done[t*B_ + b] ? 0.f : 1.f;
        float* cst = ws + (l ? WS_C1 : WS_C0) + (size_t)b*H_ + h;
        float cp = ((t == 0) ? c0in[(size_t)l*B_*H_ + b*H_ + h] : *cst) * nd;
        const float gi = gates[0][hi][j], gf = gates[1][hi][j];
        const float gv = gates[2][hi][j], go = gates[3][hi][j];
        const float ii = 1.f/(1.f + expf(-gi));
        const float ff = 1.f/(1.f + expf(-gf));
        const float gt = tanhf(gv);
        const float oo = 1.f/(1.f + expf(-go));
        const float cl = ff*cp + ii*gt;
        *cst = cl;
        float* hout = ws + (l ? WS_H1 : WS_H0) + (size_t)(t&1)*B_*H_;
        hout[(size_t)b*H_ + h] = oo*tanhf(cl);
    }

    // ---- argmax for head step (hlog filled before the barrier) ----
    if (dohead && tid == 0) {
        const int th = d - 2;
        float best = hlog[0]; int bi = 0;
        #pragma unroll
        for (int a = 1; a < A_; ++a) { float v = hlog[a]; if (v > best) { best = v; bi = a; } }
        out[OUT_ACT + th*B_ + wl] = (float)bi;       // strict > = first-max, matches np
    }

    // ---- final state copy ----
    if (l == 1 && d == 513 && tid < 256) {
        const int idx = wl*H_ + tid;                 // b*H + h
        out[OUT_HT + idx]         = ws[WS_H0 + B_*H_ + idx];   // h(511) parity 1
        out[OUT_HT + B_*H_ + idx] = ws[WS_H1 + B_*H_ + idx];
        out[OUT_CT + idx]         = ws[WS_C0 + idx];
        out[OUT_CT + B_*H_ + idx] = ws[WS_C1 + idx];
    }
}

extern "C" void kernel_launch(void* const* d_in, const int* in_sizes, int n_in,
                              void* d_out, int out_size, void* d_ws, size_t ws_size,
                              hipStream_t stream)
{
    const float* x    = (const float*)d_in[0];
    const int*   done = (const int*)  d_in[1];
    const float* h0   = (const float*)d_in[2];
    const float* c0   = (const float*)d_in[3];
    const float* w_ih = (const float*)d_in[4];
    const float* w_hh = (const float*)d_in[5];
    const float* b_ih = (const float*)d_in[6];
    const float* b_hh = (const float*)d_in[7];
    const float* Wp   = (const float*)d_in[8];
    const float* bp   = (const float*)d_in[9];
    const float* Wb   = (const float*)d_in[10];
    const float* bb   = (const float*)d_in[11];
    float* out = (float*)d_out;
    float* ws  = (float*)d_ws;    // 6*B*H floats = 768 KB

    // 514 graph-captured dispatches: d = t for L0, t+1 for L1, t+2 for head
    for (int d = 0; d < 514; ++d) {
        lstm_step<<<dim3(256), dim3(512), 0, stream>>>(
            x, done, h0, c0, w_ih, w_hh, b_ih, b_hh, Wp, bp, Wb, bb, out, ws, d);
    }
}